// Round 6
// baseline (787.563 us; speedup 1.0000x reference)
//
#include <hip/hip_runtime.h>
#include <stdint.h>

// StandardAttention: B=16, N=1024, DIM=768, H=12, Dh=64, SCALE=0.125
// cvt_all -> gemm_bt<0,256> qkv (q*0.125*log2e, k, V TRANSPOSED)
// -> flash_attn (S^T, 2^x, no online max, l via MFMA-ones) -> gemm_bt<1,128>(+bias).

typedef unsigned short u16;
typedef __attribute__((ext_vector_type(8))) short s16x8;   // 8 x bf16 MFMA frag
typedef __attribute__((ext_vector_type(4))) float f32x4;   // MFMA accum
typedef __attribute__((ext_vector_type(4))) unsigned short u16x4;

#define SEQ 1024
#define NHEAD 12
#define HD 64

__device__ __forceinline__ u16 f2bf(float f) {
  union { float f; uint32_t u; } v; v.f = f;
  uint32_t u = v.u;
  return (u16)((u + 0x7FFFu + ((u >> 16) & 1u)) >> 16);   // RNE
}

// 2^x via v_exp_f32 (native). NOTE: __exp2f collides with glibc math.h.
__device__ __forceinline__ float exp2_fast(float x) {
  return __builtin_amdgcn_exp2f(x);
}

// pack two f32 -> bf16x2 (lo=a, hi=b)
__device__ __forceinline__ uint32_t pk_bf16(float a, float b) {
#if __has_builtin(__builtin_amdgcn_cvt_pk_bf16_f32)
  typedef __attribute__((ext_vector_type(2))) __bf16 bf2;
  union { bf2 v; uint32_t u; } c;
  c.v = __builtin_amdgcn_cvt_pk_bf16_f32(a, b);
  return c.u;
#else
  union { float f; uint32_t u; } ua, ub; ua.f = a; ub.f = b;
  const uint32_t ra = ua.u + 0x8000u, rb = ub.u + 0x8000u;
  return __builtin_amdgcn_perm(ra, rb, 0x03020706u);
#endif
}

__device__ __forceinline__ void gld_lds16(const void* g, void* l) {
  __builtin_amdgcn_global_load_lds((const __attribute__((address_space(1))) void*)g,
                                   (__attribute__((address_space(3))) void*)l, 16, 0, 0);
}

// one launch converts x, w_qkv, w_proj (float4-vectorized)
__global__ void cvt_all(const float* __restrict__ x, const float* __restrict__ wq,
                        const float* __restrict__ wp,
                        u16* __restrict__ xo, u16* __restrict__ wqo, u16* __restrict__ wpo,
                        int n4x, int n4wq, int n4all) {
  int i = blockIdx.x * blockDim.x + threadIdx.x;
  if (i >= n4all) return;
  const float* in; u16* out; int j = i;
  if (i < n4x)            { in = x;  out = xo; }
  else if (i < n4x + n4wq){ in = wq; out = wqo; j = i - n4x; }
  else                    { in = wp; out = wpo; j = i - n4x - n4wq; }
  float4 f = ((const float4*)in)[j];
  u16x4 o;
  o.x = f2bf(f.x); o.y = f2bf(f.y); o.z = f2bf(f.z); o.w = f2bf(f.w);
  ((u16x4*)out)[j] = o;
}

// C = A[M,768] @ B^T, B row-major [N,768]. BMx128 tile, BK=64.
// BM=128: 256 thr / 4 waves (2m x 2n); BM=256: 512 thr / 8 waves (4m x 2n).
// EPI=0: scatter q(*0.125*log2e)/k to [B,H,N,64], V TRANSPOSED to [B,H,64,N].
// EPI=1: +bias, fp32 out.
template <int EPI, int BM>
__global__ __launch_bounds__(BM * 2, 3 * BM / 128)
void gemm_bt(const u16* __restrict__ A, const u16* __restrict__ B,
             u16* __restrict__ q, u16* __restrict__ k, u16* __restrict__ v,
             float* __restrict__ out, const float* __restrict__ bias) {
  constexpr int MW = BM / 64;          // waves along m
  constexpr int NWAVES = 2 * MW;
  constexpr int TPW_B = 16 / NWAVES;   // B staging insts per wave
  __shared__ u16 As[BM * 64];
  __shared__ u16 Bs[128 * 64];
  const int tid = threadIdx.x;
  const int wv = tid >> 6, lane = tid & 63;
  const int quad = lane >> 4, l16 = lane & 15;
  const int m0 = blockIdx.x * BM, n0 = blockIdx.y * 128;
  const int wm = (wv & (MW - 1)) * 64, wn = (wv / MW) * 64;

  f32x4 acc[4][4];
#pragma unroll
  for (int i = 0; i < 4; i++)
#pragma unroll
    for (int j = 0; j < 4; j++) { acc[i][j].x = 0.f; acc[i][j].y = 0.f; acc[i][j].z = 0.f; acc[i][j].w = 0.f; }

  const int srow = (lane >> 3);
  const int scp = lane & 7;

  for (int kt = 0; kt < 768; kt += 64) {
    __syncthreads();
#pragma unroll
    for (int i = 0; i < 4; i++) {      // A: 4 insts/wave, rows t*8..t*8+7
      const int t = wv * 4 + i;
      const int row = t * 8 + srow;
      const int c = scp ^ (row & 7);
      gld_lds16(A + (size_t)(m0 + row) * 768 + kt + c * 8, &As[t * 512]);
    }
#pragma unroll
    for (int i = 0; i < TPW_B; i++) {  // B: TPW_B insts/wave
      const int t = wv * TPW_B + i;
      const int row = t * 8 + srow;
      const int c = scp ^ (row & 7);
      gld_lds16(B + (size_t)(n0 + row) * 768 + kt + c * 8, &Bs[t * 512]);
    }
    __syncthreads();
#pragma unroll
    for (int ks = 0; ks < 2; ks++) {
      s16x8 af[4], bf[4];
#pragma unroll
      for (int mi = 0; mi < 4; mi++) {
        const int ra = wm + mi * 16 + l16;
        const int ca = ((ks * 4 + quad) ^ (ra & 7)) * 8;
        af[mi] = *(const s16x8*)&As[ra * 64 + ca];
        const int rb = wn + mi * 16 + l16;
        const int cb = ((ks * 4 + quad) ^ (rb & 7)) * 8;
        bf[mi] = *(const s16x8*)&Bs[rb * 64 + cb];
      }
#pragma unroll
      for (int mi = 0; mi < 4; mi++)
#pragma unroll
        for (int ni = 0; ni < 4; ni++)
          acc[mi][ni] = __builtin_amdgcn_mfma_f32_16x16x32_bf16(af[mi], bf[ni], acc[mi][ni], 0, 0, 0);
    }
  }

#pragma unroll
  for (int mi = 0; mi < 4; mi++) {
#pragma unroll
    for (int ni = 0; ni < 4; ni++) {
#pragma unroll
      for (int r = 0; r < 4; r++) {
        const int m = m0 + wm + mi * 16 + quad * 4 + r;
        const int n = n0 + wn + ni * 16 + l16;
        const float val = acc[mi][ni][r];
        if (EPI == 0) {
          const int which = n / 768;
          const int rc = n % 768;
          const int head = rc >> 6, d = rc & 63;
          const int b = m >> 10, rr = m & 1023;
          if (which == 0)   // fold SCALE * log2(e) so flash uses 2^x directly
            q[((size_t)(b * NHEAD + head) * SEQ + rr) * HD + d] = f2bf(val * 0.18033688011112042f);
          else if (which == 1)
            k[((size_t)(b * NHEAD + head) * SEQ + rr) * HD + d] = f2bf(val);
          else
            v[((size_t)(b * NHEAD + head) * HD + d) * SEQ + rr] = f2bf(val);
        } else {
          out[(size_t)m * 768 + n] = val + bias[n];
        }
      }
    }
  }
}

// Flash attention, S^T form, no online max, 2^x, double-buffered K/V staging.
// l computed as P @ ones via MFMA (acc_l lands in same C-layout rows as acc).
__global__ __launch_bounds__(256, 3)
void flash_attn(const u16* __restrict__ Q, const u16* __restrict__ K,
                const u16* __restrict__ VT, u16* __restrict__ O) {
  __shared__ u16 Ks[2][64 * 64];        // [key][d], chunks swizzled by key&7
  __shared__ u16 Vs[2][64 * 64];        // [d][key], chunks swizzled by d&7
  __shared__ u16 Ps[4][32 * 64];        // per-wave [qrow][key]

  const int tid = threadIdx.x;
  const int wv = tid >> 6, lane = tid & 63;
  const int quad = lane >> 4, l16 = lane & 15;
  const int bh = blockIdx.x;
  const int q0 = blockIdx.y * 128 + wv * 32;
  const size_t base = (size_t)bh * SEQ * HD;
  const size_t vbase = (size_t)bh * HD * SEQ;
  u16* pw = Ps[wv];

  const int sr0 = tid >> 3;
  const int sc0 = (tid & 7) ^ (sr0 & 7);
  const int sr1 = 32 + sr0;
  const int sc1 = (tid & 7) ^ (sr1 & 7);

  s16x8 qf[2][2];
#pragma unroll
  for (int g = 0; g < 2; g++)
#pragma unroll
    for (int ks = 0; ks < 2; ks++)
      qf[g][ks] = *(const s16x8*)(Q + base + (size_t)(q0 + g * 16 + l16) * HD + ks * 32 + quad * 8);

  const s16x8 ones = {0x3F80, 0x3F80, 0x3F80, 0x3F80, 0x3F80, 0x3F80, 0x3F80, 0x3F80};

  f32x4 acc[2][4], acc_l[2];
#pragma unroll
  for (int g = 0; g < 2; g++) {
    acc_l[g].x = 0.f; acc_l[g].y = 0.f; acc_l[g].z = 0.f; acc_l[g].w = 0.f;
#pragma unroll
    for (int t = 0; t < 4; t++) { acc[g][t].x = 0.f; acc[g][t].y = 0.f; acc[g][t].z = 0.f; acc[g][t].w = 0.f; }
  }

  const int swz = l16 & 7;

  gld_lds16(K + base + (size_t)sr0 * HD + sc0 * 8, &Ks[0][wv * 512]);
  gld_lds16(VT + vbase + (size_t)sr0 * SEQ + sc0 * 8, &Vs[0][wv * 512]);
  gld_lds16(K + base + (size_t)sr1 * HD + sc1 * 8, &Ks[0][2048 + wv * 512]);
  gld_lds16(VT + vbase + (size_t)sr1 * SEQ + sc1 * 8, &Vs[0][2048 + wv * 512]);

  for (int it = 0; it < 16; it++) {
    __syncthreads();
    if (it + 1 < 16) {
      const int n1 = (it + 1) * 64;
      const int nb = (it + 1) & 1;
      gld_lds16(K + base + (size_t)(n1 + sr0) * HD + sc0 * 8, &Ks[nb][wv * 512]);
      gld_lds16(VT + vbase + (size_t)sr0 * SEQ + n1 + sc0 * 8, &Vs[nb][wv * 512]);
      gld_lds16(K + base + (size_t)(n1 + sr1) * HD + sc1 * 8, &Ks[nb][2048 + wv * 512]);
      gld_lds16(VT + vbase + (size_t)sr1 * SEQ + n1 + sc1 * 8, &Vs[nb][2048 + wv * 512]);
    }
    const u16* __restrict__ ks = Ks[it & 1];
    const u16* __restrict__ vs = Vs[it & 1];

    // S^T = K Q^T (q pre-scaled by 0.125*log2e)
    f32x4 s0[4], s1[4];
#pragma unroll
    for (int t = 0; t < 4; t++) {
      s0[t].x = 0.f; s0[t].y = 0.f; s0[t].z = 0.f; s0[t].w = 0.f;
      s1[t].x = 0.f; s1[t].y = 0.f; s1[t].z = 0.f; s1[t].w = 0.f;
      const u16* kr = &ks[(t * 16 + l16) * 64];
      const s16x8 kf0 = *(const s16x8*)&kr[(quad ^ swz) * 8];
      const s16x8 kf1 = *(const s16x8*)&kr[((4 + quad) ^ swz) * 8];
      s0[t] = __builtin_amdgcn_mfma_f32_16x16x32_bf16(kf0, qf[0][0], s0[t], 0, 0, 0);
      s0[t] = __builtin_amdgcn_mfma_f32_16x16x32_bf16(kf1, qf[0][1], s0[t], 0, 0, 0);
      s1[t] = __builtin_amdgcn_mfma_f32_16x16x32_bf16(kf0, qf[1][0], s1[t], 0, 0, 0);
      s1[t] = __builtin_amdgcn_mfma_f32_16x16x32_bf16(kf1, qf[1][1], s1[t], 0, 0, 0);
    }

    // p = 2^s
#pragma unroll
    for (int t = 0; t < 4; t++)
#pragma unroll
      for (int r = 0; r < 4; r++) {
        s0[t][r] = exp2_fast(s0[t][r]);
        s1[t][r] = exp2_fast(s1[t][r]);
      }

    // P -> per-wave LDS, packed b64, chunk-swizzled
#pragma unroll
    for (int t = 0; t < 4; t++) {
      const int p = (2 * t + (quad >> 1)) ^ swz;
      *(uint2*)&pw[l16 * 64 + p * 8 + (quad & 1) * 4] =
          make_uint2(pk_bf16(s0[t][0], s0[t][1]), pk_bf16(s0[t][2], s0[t][3]));
      *(uint2*)&pw[(16 + l16) * 64 + p * 8 + (quad & 1) * 4] =
          make_uint2(pk_bf16(s1[t][0], s1[t][1]), pk_bf16(s1[t][2], s1[t][3]));
    }

    // O += P V ; l += P @ ones (matrix pipe does the row sums)
#pragma unroll
    for (int ks2 = 0; ks2 < 2; ks2++) {
      const int cp = ((ks2 * 4 + quad) ^ swz) * 8;
      const s16x8 pf0 = *(const s16x8*)&pw[l16 * 64 + cp];
      const s16x8 pf1 = *(const s16x8*)&pw[(16 + l16) * 64 + cp];
      acc_l[0] = __builtin_amdgcn_mfma_f32_16x16x32_bf16(pf0, ones, acc_l[0], 0, 0, 0);
      acc_l[1] = __builtin_amdgcn_mfma_f32_16x16x32_bf16(pf1, ones, acc_l[1], 0, 0, 0);
#pragma unroll
      for (int t2 = 0; t2 < 4; t2++) {
        const s16x8 vf = *(const s16x8*)&vs[(t2 * 16 + l16) * 64 + cp];
        acc[0][t2] = __builtin_amdgcn_mfma_f32_16x16x32_bf16(pf0, vf, acc[0][t2], 0, 0, 0);
        acc[1][t2] = __builtin_amdgcn_mfma_f32_16x16x32_bf16(pf1, vf, acc[1][t2], 0, 0, 0);
      }
    }
  }

  // write attn_out bf16 [B, N, H*64]; acc_l rows coincide with acc rows
  const int b = bh / NHEAD, h = bh % NHEAD;
#pragma unroll
  for (int g = 0; g < 2; g++) {
#pragma unroll
    for (int r = 0; r < 4; r++) {
      const float li = 1.0f / acc_l[g][r];
      const int qrow = q0 + g * 16 + quad * 4 + r;
      u16* op = O + (size_t)(b * SEQ + qrow) * 768 + h * HD;
#pragma unroll
      for (int t2 = 0; t2 < 4; t2++)
        op[t2 * 16 + l16] = f2bf(acc[g][t2][r] * li);
    }
  }
}

extern "C" void kernel_launch(void* const* d_in, const int* in_sizes, int n_in,
                              void* d_out, int out_size, void* d_ws, size_t ws_size,
                              hipStream_t stream) {
  (void)in_sizes; (void)n_in; (void)out_size; (void)ws_size;
  const float* x      = (const float*)d_in[0];
  const float* w_qkv  = (const float*)d_in[1];
  const float* w_proj = (const float*)d_in[2];
  const float* b_proj = (const float*)d_in[3];

  const size_t SZ_X   = (size_t)16384 * 768;
  const size_t SZ_WQ  = (size_t)2304 * 768;
  const size_t SZ_WP  = (size_t)768 * 768;
  const size_t SZ_HED = (size_t)16 * NHEAD * SEQ * HD;

  u16* xb   = (u16*)d_ws;
  u16* wqb  = xb + SZ_X;
  u16* wpb  = wqb + SZ_WQ;
  u16* qb   = wpb + SZ_WP;
  u16* kb   = qb + SZ_HED;
  u16* vtb  = kb + SZ_HED;     // V transposed [bh][d][n]
  u16* attn = vtb + SZ_HED;

  const int n4x  = (int)(SZ_X / 4);
  const int n4wq = (int)(SZ_WQ / 4);
  const int n4a  = (int)((SZ_X + SZ_WQ + SZ_WP) / 4);
  cvt_all<<<(n4a + 255) / 256, 256, 0, stream>>>(x, w_qkv, w_proj, xb, wqb, wpb,
                                                 n4x, n4wq, n4a);

  gemm_bt<0, 256><<<dim3(64, 18), 512, 0, stream>>>(xb, wqb, qb, kb, vtb, nullptr, nullptr);
  flash_attn<<<dim3(192, 8), 256, 0, stream>>>(qb, kb, vtb, attn);
  gemm_bt<1, 128><<<dim3(128, 6), 256, 0, stream>>>(attn, wpb, nullptr, nullptr, nullptr,
                                                    (float*)d_out, b_proj);
}

// Round 7
// 323.409 us; speedup vs baseline: 2.4352x; 2.4352x over previous
//
#include <hip/hip_runtime.h>
#include <stdint.h>

// StandardAttention: B=16, N=1024, DIM=768, H=12, Dh=64, SCALE=0.125
// cvt_all -> gemm_bt<0,256> qkv (q*0.125*log2e, k, V TRANSPOSED)
// -> flash_attn (S^T, 2^x, no online max, l via MFMA-ones) -> gemm_bt<1,128>(+bias).
// R7 fix: BM=256 launch_bounds min-waves/EU = 2 (r6's "6" capped VGPRs at ~85
// and spilled acc to scratch: 1.7 GB writes, 616 us).

typedef unsigned short u16;
typedef __attribute__((ext_vector_type(8))) short s16x8;   // 8 x bf16 MFMA frag
typedef __attribute__((ext_vector_type(4))) float f32x4;   // MFMA accum
typedef __attribute__((ext_vector_type(4))) unsigned short u16x4;

#define SEQ 1024
#define NHEAD 12
#define HD 64

__device__ __forceinline__ u16 f2bf(float f) {
  union { float f; uint32_t u; } v; v.f = f;
  uint32_t u = v.u;
  return (u16)((u + 0x7FFFu + ((u >> 16) & 1u)) >> 16);   // RNE
}

// 2^x via v_exp_f32 (native). NOTE: __exp2f collides with glibc math.h.
__device__ __forceinline__ float exp2_fast(float x) {
  return __builtin_amdgcn_exp2f(x);
}

// pack two f32 -> bf16x2 (lo=a, hi=b)
__device__ __forceinline__ uint32_t pk_bf16(float a, float b) {
#if __has_builtin(__builtin_amdgcn_cvt_pk_bf16_f32)
  typedef __attribute__((ext_vector_type(2))) __bf16 bf2;
  union { bf2 v; uint32_t u; } c;
  c.v = __builtin_amdgcn_cvt_pk_bf16_f32(a, b);
  return c.u;
#else
  union { float f; uint32_t u; } ua, ub; ua.f = a; ub.f = b;
  const uint32_t ra = ua.u + 0x8000u, rb = ub.u + 0x8000u;
  return __builtin_amdgcn_perm(ra, rb, 0x03020706u);
#endif
}

__device__ __forceinline__ void gld_lds16(const void* g, void* l) {
  __builtin_amdgcn_global_load_lds((const __attribute__((address_space(1))) void*)g,
                                   (__attribute__((address_space(3))) void*)l, 16, 0, 0);
}

// one launch converts x, w_qkv, w_proj (float4-vectorized)
__global__ void cvt_all(const float* __restrict__ x, const float* __restrict__ wq,
                        const float* __restrict__ wp,
                        u16* __restrict__ xo, u16* __restrict__ wqo, u16* __restrict__ wpo,
                        int n4x, int n4wq, int n4all) {
  int i = blockIdx.x * blockDim.x + threadIdx.x;
  if (i >= n4all) return;
  const float* in; u16* out; int j = i;
  if (i < n4x)            { in = x;  out = xo; }
  else if (i < n4x + n4wq){ in = wq; out = wqo; j = i - n4x; }
  else                    { in = wp; out = wpo; j = i - n4x - n4wq; }
  float4 f = ((const float4*)in)[j];
  u16x4 o;
  o.x = f2bf(f.x); o.y = f2bf(f.y); o.z = f2bf(f.z); o.w = f2bf(f.w);
  ((u16x4*)out)[j] = o;
}

// C = A[M,768] @ B^T, B row-major [N,768]. BMx128 tile, BK=64.
// BM=128: 256 thr / 4 waves (2m x 2n), 3 blocks/CU; BM=256: 512 thr / 8 waves
// (4m x 2n), 2 blocks/CU (VGPR ~120 -> 4 waves/SIMD).
// EPI=0: scatter q(*0.125*log2e)/k to [B,H,N,64], V TRANSPOSED to [B,H,64,N].
// EPI=1: +bias, fp32 out.
template <int EPI, int BM>
__global__ __launch_bounds__(BM * 2, BM == 256 ? 2 : 3)
void gemm_bt(const u16* __restrict__ A, const u16* __restrict__ B,
             u16* __restrict__ q, u16* __restrict__ k, u16* __restrict__ v,
             float* __restrict__ out, const float* __restrict__ bias) {
  constexpr int MW = BM / 64;          // waves along m
  constexpr int NWAVES = 2 * MW;
  constexpr int TPW_B = 16 / NWAVES;   // B staging insts per wave
  __shared__ u16 As[BM * 64];
  __shared__ u16 Bs[128 * 64];
  const int tid = threadIdx.x;
  const int wv = tid >> 6, lane = tid & 63;
  const int quad = lane >> 4, l16 = lane & 15;
  const int m0 = blockIdx.x * BM, n0 = blockIdx.y * 128;
  const int wm = (wv & (MW - 1)) * 64, wn = (wv / MW) * 64;

  f32x4 acc[4][4];
#pragma unroll
  for (int i = 0; i < 4; i++)
#pragma unroll
    for (int j = 0; j < 4; j++) { acc[i][j].x = 0.f; acc[i][j].y = 0.f; acc[i][j].z = 0.f; acc[i][j].w = 0.f; }

  const int srow = (lane >> 3);
  const int scp = lane & 7;

  for (int kt = 0; kt < 768; kt += 64) {
    __syncthreads();
#pragma unroll
    for (int i = 0; i < 4; i++) {      // A: 4 insts/wave, rows t*8..t*8+7
      const int t = wv * 4 + i;
      const int row = t * 8 + srow;
      const int c = scp ^ (row & 7);
      gld_lds16(A + (size_t)(m0 + row) * 768 + kt + c * 8, &As[t * 512]);
    }
#pragma unroll
    for (int i = 0; i < TPW_B; i++) {  // B: TPW_B insts/wave
      const int t = wv * TPW_B + i;
      const int row = t * 8 + srow;
      const int c = scp ^ (row & 7);
      gld_lds16(B + (size_t)(n0 + row) * 768 + kt + c * 8, &Bs[t * 512]);
    }
    __syncthreads();
#pragma unroll
    for (int ks = 0; ks < 2; ks++) {
      s16x8 af[4], bf[4];
#pragma unroll
      for (int mi = 0; mi < 4; mi++) {
        const int ra = wm + mi * 16 + l16;
        const int ca = ((ks * 4 + quad) ^ (ra & 7)) * 8;
        af[mi] = *(const s16x8*)&As[ra * 64 + ca];
        const int rb = wn + mi * 16 + l16;
        const int cb = ((ks * 4 + quad) ^ (rb & 7)) * 8;
        bf[mi] = *(const s16x8*)&Bs[rb * 64 + cb];
      }
#pragma unroll
      for (int mi = 0; mi < 4; mi++)
#pragma unroll
        for (int ni = 0; ni < 4; ni++)
          acc[mi][ni] = __builtin_amdgcn_mfma_f32_16x16x32_bf16(af[mi], bf[ni], acc[mi][ni], 0, 0, 0);
    }
  }

#pragma unroll
  for (int mi = 0; mi < 4; mi++) {
#pragma unroll
    for (int ni = 0; ni < 4; ni++) {
#pragma unroll
      for (int r = 0; r < 4; r++) {
        const int m = m0 + wm + mi * 16 + quad * 4 + r;
        const int n = n0 + wn + ni * 16 + l16;
        const float val = acc[mi][ni][r];
        if (EPI == 0) {
          const int which = n / 768;
          const int rc = n % 768;
          const int head = rc >> 6, d = rc & 63;
          const int b = m >> 10, rr = m & 1023;
          if (which == 0)   // fold SCALE * log2(e) so flash uses 2^x directly
            q[((size_t)(b * NHEAD + head) * SEQ + rr) * HD + d] = f2bf(val * 0.18033688011112042f);
          else if (which == 1)
            k[((size_t)(b * NHEAD + head) * SEQ + rr) * HD + d] = f2bf(val);
          else
            v[((size_t)(b * NHEAD + head) * HD + d) * SEQ + rr] = f2bf(val);
        } else {
          out[(size_t)m * 768 + n] = val + bias[n];
        }
      }
    }
  }
}

// Flash attention, S^T form, no online max, 2^x, double-buffered K/V staging.
// l computed as P @ ones via MFMA (acc_l lands in same C-layout rows as acc).
__global__ __launch_bounds__(256, 3)
void flash_attn(const u16* __restrict__ Q, const u16* __restrict__ K,
                const u16* __restrict__ VT, u16* __restrict__ O) {
  __shared__ u16 Ks[2][64 * 64];        // [key][d], chunks swizzled by key&7
  __shared__ u16 Vs[2][64 * 64];        // [d][key], chunks swizzled by d&7
  __shared__ u16 Ps[4][32 * 64];        // per-wave [qrow][key]

  const int tid = threadIdx.x;
  const int wv = tid >> 6, lane = tid & 63;
  const int quad = lane >> 4, l16 = lane & 15;
  const int bh = blockIdx.x;
  const int q0 = blockIdx.y * 128 + wv * 32;
  const size_t base = (size_t)bh * SEQ * HD;
  const size_t vbase = (size_t)bh * HD * SEQ;
  u16* pw = Ps[wv];

  const int sr0 = tid >> 3;
  const int sc0 = (tid & 7) ^ (sr0 & 7);
  const int sr1 = 32 + sr0;
  const int sc1 = (tid & 7) ^ (sr1 & 7);

  s16x8 qf[2][2];
#pragma unroll
  for (int g = 0; g < 2; g++)
#pragma unroll
    for (int ks = 0; ks < 2; ks++)
      qf[g][ks] = *(const s16x8*)(Q + base + (size_t)(q0 + g * 16 + l16) * HD + ks * 32 + quad * 8);

  const s16x8 ones = {0x3F80, 0x3F80, 0x3F80, 0x3F80, 0x3F80, 0x3F80, 0x3F80, 0x3F80};

  f32x4 acc[2][4], acc_l[2];
#pragma unroll
  for (int g = 0; g < 2; g++) {
    acc_l[g].x = 0.f; acc_l[g].y = 0.f; acc_l[g].z = 0.f; acc_l[g].w = 0.f;
#pragma unroll
    for (int t = 0; t < 4; t++) { acc[g][t].x = 0.f; acc[g][t].y = 0.f; acc[g][t].z = 0.f; acc[g][t].w = 0.f; }
  }

  const int swz = l16 & 7;

  gld_lds16(K + base + (size_t)sr0 * HD + sc0 * 8, &Ks[0][wv * 512]);
  gld_lds16(VT + vbase + (size_t)sr0 * SEQ + sc0 * 8, &Vs[0][wv * 512]);
  gld_lds16(K + base + (size_t)sr1 * HD + sc1 * 8, &Ks[0][2048 + wv * 512]);
  gld_lds16(VT + vbase + (size_t)sr1 * SEQ + sc1 * 8, &Vs[0][2048 + wv * 512]);

  for (int it = 0; it < 16; it++) {
    __syncthreads();
    if (it + 1 < 16) {
      const int n1 = (it + 1) * 64;
      const int nb = (it + 1) & 1;
      gld_lds16(K + base + (size_t)(n1 + sr0) * HD + sc0 * 8, &Ks[nb][wv * 512]);
      gld_lds16(VT + vbase + (size_t)sr0 * SEQ + n1 + sc0 * 8, &Vs[nb][wv * 512]);
      gld_lds16(K + base + (size_t)(n1 + sr1) * HD + sc1 * 8, &Ks[nb][2048 + wv * 512]);
      gld_lds16(VT + vbase + (size_t)sr1 * SEQ + n1 + sc1 * 8, &Vs[nb][2048 + wv * 512]);
    }
    const u16* __restrict__ ks = Ks[it & 1];
    const u16* __restrict__ vs = Vs[it & 1];

    // S^T = K Q^T (q pre-scaled by 0.125*log2e)
    f32x4 s0[4], s1[4];
#pragma unroll
    for (int t = 0; t < 4; t++) {
      s0[t].x = 0.f; s0[t].y = 0.f; s0[t].z = 0.f; s0[t].w = 0.f;
      s1[t].x = 0.f; s1[t].y = 0.f; s1[t].z = 0.f; s1[t].w = 0.f;
      const u16* kr = &ks[(t * 16 + l16) * 64];
      const s16x8 kf0 = *(const s16x8*)&kr[(quad ^ swz) * 8];
      const s16x8 kf1 = *(const s16x8*)&kr[((4 + quad) ^ swz) * 8];
      s0[t] = __builtin_amdgcn_mfma_f32_16x16x32_bf16(kf0, qf[0][0], s0[t], 0, 0, 0);
      s0[t] = __builtin_amdgcn_mfma_f32_16x16x32_bf16(kf1, qf[0][1], s0[t], 0, 0, 0);
      s1[t] = __builtin_amdgcn_mfma_f32_16x16x32_bf16(kf0, qf[1][0], s1[t], 0, 0, 0);
      s1[t] = __builtin_amdgcn_mfma_f32_16x16x32_bf16(kf1, qf[1][1], s1[t], 0, 0, 0);
    }

    // p = 2^s
#pragma unroll
    for (int t = 0; t < 4; t++)
#pragma unroll
      for (int r = 0; r < 4; r++) {
        s0[t][r] = exp2_fast(s0[t][r]);
        s1[t][r] = exp2_fast(s1[t][r]);
      }

    // P -> per-wave LDS, packed b64, chunk-swizzled
#pragma unroll
    for (int t = 0; t < 4; t++) {
      const int p = (2 * t + (quad >> 1)) ^ swz;
      *(uint2*)&pw[l16 * 64 + p * 8 + (quad & 1) * 4] =
          make_uint2(pk_bf16(s0[t][0], s0[t][1]), pk_bf16(s0[t][2], s0[t][3]));
      *(uint2*)&pw[(16 + l16) * 64 + p * 8 + (quad & 1) * 4] =
          make_uint2(pk_bf16(s1[t][0], s1[t][1]), pk_bf16(s1[t][2], s1[t][3]));
    }

    // O += P V ; l += P @ ones (matrix pipe does the row sums)
#pragma unroll
    for (int ks2 = 0; ks2 < 2; ks2++) {
      const int cp = ((ks2 * 4 + quad) ^ swz) * 8;
      const s16x8 pf0 = *(const s16x8*)&pw[l16 * 64 + cp];
      const s16x8 pf1 = *(const s16x8*)&pw[(16 + l16) * 64 + cp];
      acc_l[0] = __builtin_amdgcn_mfma_f32_16x16x32_bf16(pf0, ones, acc_l[0], 0, 0, 0);
      acc_l[1] = __builtin_amdgcn_mfma_f32_16x16x32_bf16(pf1, ones, acc_l[1], 0, 0, 0);
#pragma unroll
      for (int t2 = 0; t2 < 4; t2++) {
        const s16x8 vf = *(const s16x8*)&vs[(t2 * 16 + l16) * 64 + cp];
        acc[0][t2] = __builtin_amdgcn_mfma_f32_16x16x32_bf16(pf0, vf, acc[0][t2], 0, 0, 0);
        acc[1][t2] = __builtin_amdgcn_mfma_f32_16x16x32_bf16(pf1, vf, acc[1][t2], 0, 0, 0);
      }
    }
  }

  // write attn_out bf16 [B, N, H*64]; acc_l rows coincide with acc rows
  const int b = bh / NHEAD, h = bh % NHEAD;
#pragma unroll
  for (int g = 0; g < 2; g++) {
#pragma unroll
    for (int r = 0; r < 4; r++) {
      const float li = 1.0f / acc_l[g][r];
      const int qrow = q0 + g * 16 + quad * 4 + r;
      u16* op = O + (size_t)(b * SEQ + qrow) * 768 + h * HD;
#pragma unroll
      for (int t2 = 0; t2 < 4; t2++)
        op[t2 * 16 + l16] = f2bf(acc[g][t2][r] * li);
    }
  }
}

extern "C" void kernel_launch(void* const* d_in, const int* in_sizes, int n_in,
                              void* d_out, int out_size, void* d_ws, size_t ws_size,
                              hipStream_t stream) {
  (void)in_sizes; (void)n_in; (void)out_size; (void)ws_size;
  const float* x      = (const float*)d_in[0];
  const float* w_qkv  = (const float*)d_in[1];
  const float* w_proj = (const float*)d_in[2];
  const float* b_proj = (const float*)d_in[3];

  const size_t SZ_X   = (size_t)16384 * 768;
  const size_t SZ_WQ  = (size_t)2304 * 768;
  const size_t SZ_WP  = (size_t)768 * 768;
  const size_t SZ_HED = (size_t)16 * NHEAD * SEQ * HD;

  u16* xb   = (u16*)d_ws;
  u16* wqb  = xb + SZ_X;
  u16* wpb  = wqb + SZ_WQ;
  u16* qb   = wpb + SZ_WP;
  u16* kb   = qb + SZ_HED;
  u16* vtb  = kb + SZ_HED;     // V transposed [bh][d][n]
  u16* attn = vtb + SZ_HED;

  const int n4x  = (int)(SZ_X / 4);
  const int n4wq = (int)(SZ_WQ / 4);
  const int n4a  = (int)((SZ_X + SZ_WQ + SZ_WP) / 4);
  cvt_all<<<(n4a + 255) / 256, 256, 0, stream>>>(x, w_qkv, w_proj, xb, wqb, wpb,
                                                 n4x, n4wq, n4a);

  gemm_bt<0, 256><<<dim3(64, 18), 512, 0, stream>>>(xb, wqb, qb, kb, vtb, nullptr, nullptr);
  flash_attn<<<dim3(192, 8), 256, 0, stream>>>(qb, kb, vtb, attn);
  gemm_bt<1, 128><<<dim3(128, 6), 256, 0, stream>>>(attn, wpb, nullptr, nullptr, nullptr,
                                                    (float*)d_out, b_proj);
}